// Round 9
// baseline (66752.228 us; speedup 1.0000x reference)
//
#include <hip/hip_runtime.h>

// ---------------------------------------------------------------------------
// TransitionDown: FPS (M=N/4) -> KNN(K=16) -> Linear(64->128)+ReLU -> max-pool
// Round 9: collapse FPS serial chains. R8 evidence: u64 shfl reduces (2x
// ds_bpermute each, 6 DEPENDENT rounds) + wave0-only 512-key scan + 2
// barriers + ~900cyc HBM spts pull = 9.3Kcyc/step. Changes:
//  - ONE barrier/step: parity double-buffered gkey/gpt; pre-barrier work is
//    wave-local (own 32 slots); post-barrier ALL waves redundantly scan the
//    512 keys and compute the pick (no wave0 serialization, no 2nd barrier).
//  - radix-8 two-level reduces (independent shuffles: 2 latency exposures
//    instead of 6).
//  - mindS read issued parallel with spts load.
// Exactness unchanged: key=(bits(mind)<<32)|(0xffffffff-origIdx), u64-max =
// max mind, tie -> lowest ORIGINAL index; conservative ball-bound skip.
// ---------------------------------------------------------------------------

#define FPS_T   1024
#define NG      512          // N/64 groups
#define NPTS    32768
#define NCELL   4096
#define KNN_K   16
#define MLP_ROWS 32

__device__ __forceinline__ int cell_key(float x, float y, float z)
{
    int qx = (int)((x + 6.0f) * 1.3333333f);
    int qy = (int)((y + 6.0f) * 1.3333333f);
    int qz = (int)((z + 6.0f) * 1.3333333f);
    qx = qx < 0 ? 0 : (qx > 15 ? 15 : qx);
    qy = qy < 0 ? 0 : (qy > 15 ? 15 : qy);
    qz = qz < 0 ? 0 : (qz > 15 ? 15 : qz);
    auto spread = [](int v) {
        return (v & 1) | ((v & 2) << 2) | ((v & 4) << 4) | ((v & 8) << 6);
    };
    return spread(qx) | (spread(qy) << 1) | (spread(qz) << 2);
}

// --- SoA transpose of pos (for KNN) ----------------------------------------
__global__ void prep_kernel(const float* __restrict__ pos, float* __restrict__ posx,
                            float* __restrict__ posy, float* __restrict__ posz, int N)
{
    const int i = blockIdx.x * blockDim.x + threadIdx.x;
    if (i < N) {
        posx[i] = pos[3 * i + 0];
        posy[i] = pos[3 * i + 1];
        posz[i] = pos[3 * i + 2];
    }
}

// --- counting sort by Morton cell ------------------------------------------
__global__ void zero_kernel(int* __restrict__ hist)
{
    hist[blockIdx.x * blockDim.x + threadIdx.x] = 0;
}

__global__ void hist_kernel(const float* __restrict__ pos, int* __restrict__ hist, int N)
{
    const int i = blockIdx.x * blockDim.x + threadIdx.x;
    if (i < N)
        atomicAdd(&hist[cell_key(pos[3 * i], pos[3 * i + 1], pos[3 * i + 2])], 1);
}

__global__ __launch_bounds__(1024) void scan_kernel(int* __restrict__ hist)
{
    __shared__ int part[1024];
    const int t = threadIdx.x;
    const int v0 = hist[t * 4 + 0], v1 = hist[t * 4 + 1];
    const int v2 = hist[t * 4 + 2], v3 = hist[t * 4 + 3];
    const int tot = v0 + v1 + v2 + v3;
    int acc = tot;
    part[t] = acc;
    __syncthreads();
    for (int off = 1; off < 1024; off <<= 1) {
        const int add = (t >= off) ? part[t - off] : 0;
        __syncthreads();
        acc += add;
        part[t] = acc;
        __syncthreads();
    }
    const int ex = acc - tot;
    hist[t * 4 + 0] = ex;
    hist[t * 4 + 1] = ex + v0;
    hist[t * 4 + 2] = ex + v0 + v1;
    hist[t * 4 + 3] = ex + v0 + v1 + v2;
}

__global__ void scatter_kernel(const float* __restrict__ pos, int* __restrict__ cellptr,
                               float4* __restrict__ spts, int N)
{
    const int i = blockIdx.x * blockDim.x + threadIdx.x;
    if (i < N) {
        const float x = pos[3 * i], y = pos[3 * i + 1], z = pos[3 * i + 2];
        const int dst = atomicAdd(&cellptr[cell_key(x, y, z)], 1);
        spts[dst] = make_float4(x, y, z, __int_as_float(i));   // .w = original index
    }
}

// --- per-group ball: centroid + conservative radius ------------------------
__global__ __launch_bounds__(256) void grpmeta_kernel(const float4* __restrict__ spts,
                                                      float4* __restrict__ grp, int ngroups)
{
    const int g = (int)((blockIdx.x * (unsigned)blockDim.x + threadIdx.x) >> 6);
    const int lane = threadIdx.x & 63;
    if (g >= ngroups) return;
    const float4 p = spts[(g << 6) + lane];
    float sx = p.x, sy = p.y, sz = p.z;
#pragma unroll
    for (int off = 32; off; off >>= 1) {
        sx += __shfl_xor(sx, off);
        sy += __shfl_xor(sy, off);
        sz += __shfl_xor(sz, off);
    }
    const float cx = sx * (1.0f / 64.0f), cy = sy * (1.0f / 64.0f), cz = sz * (1.0f / 64.0f);
    const float dx = p.x - cx, dy = p.y - cy, dz = p.z - cz;
    float d2 = dx * dx + dy * dy + dz * dz;
#pragma unroll
    for (int off = 32; off; off >>= 1) d2 = fmaxf(d2, __shfl_xor(d2, off));
    if (lane == 0)
        grp[g] = make_float4(cx, cy, cz, sqrtf(d2) * 1.0005f + 1e-6f);
}

// --- h = relu(x @ W + b), x[N,64], W[64,128], h[N,128] ----------------------
__global__ __launch_bounds__(256) void mlp_kernel(
    const float* __restrict__ x, const float* __restrict__ W,
    const float* __restrict__ b, float* __restrict__ h, int N)
{
    __shared__ float ws[64 * 128];
    __shared__ float xs[MLP_ROWS * 65];
    const int t = threadIdx.x;
    const int r0 = blockIdx.x * MLP_ROWS;

    for (int i = t; i < 64 * 128; i += 256) ws[i] = W[i];
    for (int i = t; i < MLP_ROWS * 64; i += 256) {
        const int r = i >> 6, k = i & 63;
        xs[r * 65 + k] = x[r0 * 64 + i];
    }
    __syncthreads();

    const int tx = t & 31, ty = t >> 5;
    const int c0 = tx * 4, rr = ty * 4;
    float acc[4][4];
#pragma unroll
    for (int i = 0; i < 4; ++i)
#pragma unroll
        for (int j = 0; j < 4; ++j) acc[i][j] = 0.0f;

    for (int k = 0; k < 64; ++k) {
        const float4 w4 = *(const float4*)(&ws[k * 128 + c0]);
#pragma unroll
        for (int i = 0; i < 4; ++i) {
            const float xv = xs[(rr + i) * 65 + k];
            acc[i][0] += xv * w4.x;
            acc[i][1] += xv * w4.y;
            acc[i][2] += xv * w4.z;
            acc[i][3] += xv * w4.w;
        }
    }
    const float4 b4 = *(const float4*)(&b[c0]);
#pragma unroll
    for (int i = 0; i < 4; ++i) {
        float4 o;
        o.x = fmaxf(acc[i][0] + b4.x, 0.0f);
        o.y = fmaxf(acc[i][1] + b4.y, 0.0f);
        o.z = fmaxf(acc[i][2] + b4.z, 0.0f);
        o.w = fmaxf(acc[i][3] + b4.w, 0.0f);
        *(float4*)(&h[(size_t)(r0 + rr + i) * 128 + c0]) = o;
    }
}

// --- radix-8 two-level max over 64 lanes (key only; independent shuffles) ---
__device__ __forceinline__ unsigned long long wave_max_u64(unsigned long long k)
{
#pragma unroll
    for (int lvl = 0; lvl < 2; ++lvl) {
        const int base = lvl ? 8 : 1;
        unsigned long long v1 = __shfl_xor(k, base * 1);
        unsigned long long v2 = __shfl_xor(k, base * 2);
        unsigned long long v3 = __shfl_xor(k, base * 3);
        unsigned long long v4 = __shfl_xor(k, base * 4);
        unsigned long long v5 = __shfl_xor(k, base * 5);
        unsigned long long v6 = __shfl_xor(k, base * 6);
        unsigned long long v7 = __shfl_xor(k, base * 7);
        unsigned long long a = v1 > v2 ? v1 : v2;
        unsigned long long b = v3 > v4 ? v3 : v4;
        unsigned long long c = v5 > v6 ? v5 : v6;
        unsigned long long d = v7 > k ? v7 : k;
        a = a > b ? a : b;
        c = c > d ? c : d;
        k = a > c ? a : c;
    }
    return k;
}

// --- FPS: LDS state, 1 barrier/step, parity buffers, redundant scan ---------
// slot sg = w*32 + j  <->  sorted group g = j*16 + w.
__global__ __launch_bounds__(FPS_T) void fps4_kernel(
    const float4* __restrict__ spts, const float4* __restrict__ grp,
    const float* __restrict__ pos, int* __restrict__ out_idx, int M)
{
    const int t = threadIdx.x;
    const int w = t >> 6;
    const int lane = t & 63;

    __shared__ float mindS[NPTS];                  // 128 KB
    __shared__ unsigned long long gkey[2][NG];     // 8 KB  parity
    __shared__ float gptx[2][NG], gpty[2][NG], gptz[2][NG];  // 12 KB parity
    __shared__ float4 ballS[NG];                   // 8 KB

    for (int i = t; i < NPTS; i += FPS_T) mindS[i] = __builtin_inff();
    if (t < NG) {
        const int g = ((t & 31) << 4) | (t >> 5);  // slot t -> group g
        ballS[t] = grp[g];
        gkey[0][t] = (0x7f800000ULL << 32);        // +inf: all touched at s=1
    }
    if (t == 0) out_idx[0] = 0;
    float lx = pos[0], ly = pos[1], lz = pos[2];   // pick 0 coords (uniform)
    __syncthreads();

    for (int s = 1; s < M; ++s) {
        const int br = (s - 1) & 1;
        const int bw = s & 1;

        // ---- pre-barrier: wave-local work on its own 32 slots ----
        bool touched = false;
        unsigned long long oldkey = 0;
        int sg = 0;
        if (lane < 32) {
            sg = (w << 5) + lane;
            const float4 m4 = ballS[sg];
            oldkey = gkey[br][sg];
            const float ddx = lx - m4.x, ddy = ly - m4.y, ddz = lz - m4.z;
            const float dc = sqrtf(ddx * ddx + ddy * ddy + ddz * ddz);
            const float lb = dc - m4.w;
            const float gm = __uint_as_float((unsigned)(oldkey >> 32));
            touched = (lb <= 0.0f) || (lb * lb * 0.9995f < gm);
            if (!touched) {                         // carry forward
                gkey[bw][sg] = oldkey;
                gptx[bw][sg] = gptx[br][sg];
                gpty[bw][sg] = gpty[br][sg];
                gptz[bw][sg] = gptz[br][sg];
            }
        }
        unsigned long long mask = __ballot(touched);

        if (mask) {
            int k = __builtin_ctzll(mask);
            mask &= mask - 1;
            int base = ((((k << 4) | w)) << 6) + lane;
            float4 p = spts[base];
            float md = mindS[base];
            for (;;) {
                int kn = -1, basen = 0;
                float4 pn = p;
                float mdn = 0.0f;
                if (mask) {                          // depth-2 prefetch
                    kn = __builtin_ctzll(mask);
                    mask &= mask - 1;
                    basen = ((((kn << 4) | w)) << 6) + lane;
                    pn = spts[basen];
                    mdn = mindS[basen];
                }
                const float dx = p.x - lx;
                const float dy = p.y - ly;
                const float dz = p.z - lz;
                const float d = dx * dx + dy * dy + dz * dz;
                md = fminf(md, d);
                mindS[base] = md;
                const unsigned oi = (unsigned)__float_as_int(p.w);
                const unsigned long long mykey =
                    ((unsigned long long)__float_as_uint(md) << 32) | (0xffffffffu - oi);
                const unsigned long long key = wave_max_u64(mykey);
                const int sg2 = (w << 5) + k;
                if (lane == 0) gkey[bw][sg2] = key;
                if (mykey == key) {                  // unique winner (idx in key)
                    gptx[bw][sg2] = p.x;
                    gpty[bw][sg2] = p.y;
                    gptz[bw][sg2] = p.z;
                }
                if (kn < 0) break;
                k = kn; base = basen; p = pn; md = mdn;
            }
        }
        __syncthreads();                             // the ONLY barrier per step

        // ---- post-barrier: every wave redundantly scans all 512 keys ----
        unsigned long long bk = 0;
        int bs = 0;
#pragma unroll
        for (int j = 0; j < NG / 64; ++j) {
            const int slot = lane + (j << 6);
            const unsigned long long v = gkey[bw][slot];
            if (v > bk) { bk = v; bs = slot; }
        }
        // radix-8 two-level argmax over (bk, bs)
#pragma unroll
        for (int lvl = 0; lvl < 2; ++lvl) {
            const int base8 = lvl ? 8 : 1;
#pragma unroll
            for (int o = 1; o < 8; ++o) {
                const unsigned long long ok = __shfl_xor(bk, base8 * o);
                const int os = __shfl_xor(bs, base8 * o);
                if (ok > bk) { bk = ok; bs = os; }
            }
        }
        if (t == 0) out_idx[s] = (int)(0xffffffffu - (unsigned)(bk & 0xffffffffu));
        lx = gptx[bw][bs];                           // broadcast reads
        ly = gpty[bw][bs];
        lz = gptz[bw][bs];
        // no 2nd barrier: next step writes parity bw^1; step-s readers use bw
    }
}

// --- KNN (exact top-16 by (d, idx)) + gather-max over h + sub outputs -------
__global__ __launch_bounds__(256) void knn_kernel(
    const float* __restrict__ posx, const float* __restrict__ posy,
    const float* __restrict__ posz, const int* __restrict__ idx,
    const float* __restrict__ h, const float* __restrict__ pos,
    const int* __restrict__ batch, float* __restrict__ out,
    float* __restrict__ out_subpos, int* __restrict__ out_subbatch,
    int N, int M, int Cout)
{
    const int q = (int)((blockIdx.x * (unsigned)blockDim.x + threadIdx.x) >> 6);
    const int lane = threadIdx.x & 63;
    if (q >= M) return;

    const int qi = idx[q];
    const float qx = posx[qi], qy = posy[qi], qz = posz[qi];

    float d16[KNN_K]; int i16[KNN_K];
#pragma unroll
    for (int k = 0; k < KNN_K; ++k) { d16[k] = __builtin_inff(); i16[k] = 0x7fffffff; }
    float lmax = __builtin_inff();
    int lslot = 0;
    float T = __builtin_inff();

    const int iters = N >> 6;
    for (int c = 0; c < iters; ++c) {
        const int p = c * 64 + lane;
        const float dx = posx[p] - qx;
        const float dy = posy[p] - qy;
        const float dz = posz[p] - qz;
        const float d = dx * dx + dy * dy + dz * dz;
        if (d < T && d < lmax) {
            d16[lslot] = d; i16[lslot] = p;
            lmax = d16[0]; lslot = 0;
#pragma unroll
            for (int k = 1; k < KNN_K; ++k)
                if (d16[k] > lmax) { lmax = d16[k]; lslot = k; }
        }
        if ((c & 31) == 31) {
            float tt = lmax;
#pragma unroll
            for (int off = 32; off > 0; off >>= 1)
                tt = fminf(tt, __shfl_xor(tt, off));
            T = tt;
        }
    }

    int nbr[KNN_K];
#pragma unroll
    for (int r = 0; r < KNN_K; ++r) {
        float lv = d16[0]; int ls = 0;
#pragma unroll
        for (int k = 1; k < KNN_K; ++k)
            if (d16[k] < lv || (d16[k] == lv && i16[k] < i16[ls])) { lv = d16[k]; ls = k; }
        float mv = lv; int mi = i16[ls];
#pragma unroll
        for (int off = 32; off > 0; off >>= 1) {
            const float ov = __shfl_xor(mv, off);
            const int   oi = __shfl_xor(mi, off);
            if (ov < mv || (ov == mv && oi < mi)) { mv = ov; mi = oi; }
        }
        if (i16[ls] == mi) d16[ls] = __builtin_inff();
        nbr[r] = mi;
    }

    for (int c = lane; c < Cout; c += 64) {
        float a = -__builtin_inff();
#pragma unroll
        for (int r = 0; r < KNN_K; ++r)
            a = fmaxf(a, h[(size_t)nbr[r] * Cout + c]);
        out[(size_t)q * Cout + c] = a;
    }
    if (lane < 3) out_subpos[q * 3 + lane] = pos[qi * 3 + lane];
    if (lane == 3) out_subbatch[q] = batch[qi];
}

// ---------------------------------------------------------------------------
extern "C" void kernel_launch(void* const* d_in, const int* in_sizes, int n_in,
                              void* d_out, int out_size, void* d_ws, size_t ws_size,
                              hipStream_t stream)
{
    const float* x     = (const float*)d_in[0];
    const float* pos   = (const float*)d_in[1];
    const int*   batch = (const int*)d_in[2];
    const float* W     = (const float*)d_in[3];
    const float* b     = (const float*)d_in[4];

    const int N    = in_sizes[2];       // 32768
    const int Cout = in_sizes[4];       // 128
    const int M    = N / 4;             // 8192
    const int ngroups = N / 64;         // 512 == NG

    // ws layout: spts f4[N] | grp f4[NG] | posx,posy,posz [N] | hist [NCELL]
    //          | idx [M] | h [N*Cout]
    float4* spts = (float4*)d_ws;
    float4* grp  = spts + N;
    float*  posx = (float*)(grp + NG);
    float*  posy = posx + N;
    float*  posz = posy + N;
    int*    hist = (int*)(posz + N);
    int*    idx  = hist + NCELL;
    float*  h    = (float*)(idx + M);

    float* out          = (float*)d_out;
    float* out_subpos   = out + (size_t)M * Cout;
    int*   out_subbatch = (int*)(out_subpos + (size_t)M * 3);

    prep_kernel<<<(N + 255) / 256, 256, 0, stream>>>(pos, posx, posy, posz, N);
    zero_kernel<<<NCELL / 256, 256, 0, stream>>>(hist);
    hist_kernel<<<(N + 255) / 256, 256, 0, stream>>>(pos, hist, N);
    scan_kernel<<<1, 1024, 0, stream>>>(hist);
    scatter_kernel<<<(N + 255) / 256, 256, 0, stream>>>(pos, hist, spts, N);
    grpmeta_kernel<<<(ngroups * 64 + 255) / 256, 256, 0, stream>>>(spts, grp, ngroups);
    mlp_kernel<<<N / MLP_ROWS, 256, 0, stream>>>(x, W, b, h, N);
    fps4_kernel<<<1, FPS_T, 0, stream>>>(spts, grp, pos, idx, M);
    knn_kernel<<<(M * 64) / 256, 256, 0, stream>>>(posx, posy, posz, idx, h, pos, batch,
                                                   out, out_subpos, out_subbatch, N, M, Cout);
}